// Round 2
// baseline (53.488 us; speedup 1.0000x reference)
//
#include <hip/hip_runtime.h>

#define EMB 200
#define U_DIM 32
#define T_DIM 4
#define DIM_A 32
#define NN 10
#define WAVES 4

// ---------------- sort machinery ----------------

__global__ __launch_bounds__(256) void k_init(int* __restrict__ perm, int* __restrict__ cnt, int pb) {
    int i = blockIdx.x * 256 + threadIdx.x;
    if (i < pb) perm[i] = -1;
    if (i < 4) cnt[i] = 0;
}

__global__ __launch_bounds__(1024) void k_count(const int* __restrict__ types, int* __restrict__ cnt) {
    __shared__ int h[4];
    const int tid = threadIdx.x;
    if (tid < 4) h[tid] = 0;
    __syncthreads();
    const int b = blockIdx.x * 1024 + tid;
    const int ty = types[b];
    const int lane = tid & 63;
    #pragma unroll
    for (int tt = 0; tt < 4; ++tt) {
        if (ty == tt) {
            unsigned long long m = __ballot(1);
            if (lane == __ffsll((long long)m) - 1) atomicAdd(&h[tt], __popcll(m));
        }
    }
    __syncthreads();
    if (tid < 4) atomicAdd(&cnt[tid], h[tid]);
}

__global__ void k_base(const int* __restrict__ cnt, int* __restrict__ fill) {
    if (threadIdx.x == 0 && blockIdx.x == 0) {
        int f = 0;
        #pragma unroll
        for (int t = 0; t < 4; ++t) { fill[t] = f; f += (cnt[t] + 15) & ~15; }
    }
}

__global__ __launch_bounds__(1024) void k_scatter(const int* __restrict__ types,
                                                  int* __restrict__ fill, int* __restrict__ perm) {
    __shared__ int h[4], gb[4], woff[16][4];
    const int tid = threadIdx.x;
    const int wv = tid >> 6, lane = tid & 63;
    if (tid < 4) h[tid] = 0;
    __syncthreads();
    const int b = blockIdx.x * 1024 + tid;
    const int ty = types[b];
    int rank = 0;
    #pragma unroll
    for (int tt = 0; tt < 4; ++tt) {
        if (ty == tt) {
            unsigned long long m = __ballot(1);
            rank = __popcll(m & ((1ull << lane) - 1));
            if (lane == __ffsll((long long)m) - 1) woff[wv][tt] = atomicAdd(&h[tt], __popcll(m));
        }
    }
    __syncthreads();
    if (tid < 4) gb[tid] = atomicAdd(&fill[tid], h[tid]);
    __syncthreads();
    perm[gb[ty] + woff[wv][ty] + rank] = b;
}

// ---------------- phase A: neighbor sum + attention -> comb ----------------

__global__ __launch_bounds__(WAVES * 64) void k_comb(
    const int* __restrict__ train_types,
    const int* __restrict__ node_neigh,
    const float* __restrict__ node_type_emb,
    const float* __restrict__ tw1,
    const float* __restrict__ tw2,
    float* __restrict__ combw)
{
    __shared__ float s_nte[WAVES][T_DIM][U_DIM];

    const int wid  = threadIdx.x >> 6;
    const int lane = threadIdx.x & 63;
    const int u    = lane & 31;
    const int th   = lane >> 5;
    const int b    = blockIdx.x * WAVES + wid;

    const int type = train_types[b];

    int my_neigh = 0;
    if (lane < T_DIM * NN) my_neigh = node_neigh[b * T_DIM * NN + lane];

    #pragma unroll
    for (int tt = 0; tt < 2; ++tt) {
        const int t = tt * 2 + th;
        float acc = 0.f;
        #pragma unroll
        for (int n = 0; n < NN; ++n) {
            const int idx = __shfl(my_neigh, t * NN + n, 64);
            acc += node_type_emb[((long)idx * T_DIM + t) * U_DIM + u];
        }
        s_nte[wid][t][u] = acc;
    }
    __syncthreads();

    const float* tw1p = tw1 + type * U_DIM * DIM_A;
    const float  w2   = tw2[type * DIM_A + u];
    float sc[2];
    #pragma unroll
    for (int tt = 0; tt < 2; ++tt) {
        const int t = tt * 2 + th;
        float acc = 0.f;
        #pragma unroll
        for (int uu = 0; uu < U_DIM; ++uu)
            acc += s_nte[wid][t][uu] * tw1p[uu * DIM_A + u];
        float s = tanhf(acc) * w2;
        #pragma unroll
        for (int m = 1; m < 32; m <<= 1) s += __shfl_xor(s, m, 64);
        sc[tt] = s;
    }
    const float o0 = __shfl_xor(sc[0], 32, 64);
    const float o1 = __shfl_xor(sc[1], 32, 64);
    const float s0 = th ? o0    : sc[0];
    const float s1 = th ? sc[0] : o0;
    const float s2 = th ? o1    : sc[1];
    const float s3 = th ? sc[1] : o1;

    const float mx = fmaxf(fmaxf(s0, s1), fmaxf(s2, s3));
    const float e0 = expf(s0 - mx), e1 = expf(s1 - mx);
    const float e2 = expf(s2 - mx), e3 = expf(s3 - mx);
    const float inv = 1.f / (e0 + e1 + e2 + e3);

    const float comb = (e0 * s_nte[wid][0][u] + e1 * s_nte[wid][1][u] +
                        e2 * s_nte[wid][2][u] + e3 * s_nte[wid][3][u]) * inv;
    if (lane < 32) combw[(size_t)b * 32 + lane] = comb;
}

// ---------------- phase B: type-grouped final embed ----------------

__global__ __launch_bounds__(WAVES * 64) void k_embed(
    const int* __restrict__ train_inputs,
    const int* __restrict__ train_types,
    const int* __restrict__ perm,
    const float* __restrict__ combw,
    const float* __restrict__ node_emb,
    const float* __restrict__ tw,
    float* __restrict__ out)
{
    __shared__ float4 s_comb4[WAVES][16][8];
    __shared__ int s_bg[WAVES][16];
    __shared__ int s_node[WAVES][16];

    const int wid  = threadIdx.x >> 6;
    const int lane = threadIdx.x & 63;
    const int g = lane >> 2, q = lane & 3;
    const long base16 = (long)(blockIdx.x * WAVES + wid) * 16;

    const int bg = perm[base16 + g];
    const bool valid = bg >= 0;
    float4 c0 = make_float4(0.f, 0.f, 0.f, 0.f), c1 = c0;
    if (valid) {
        const float4* cp = (const float4*)(combw + (size_t)bg * 32 + q * 8);
        c0 = cp[0]; c1 = cp[1];
    }
    s_comb4[wid][g][q * 2]     = c0;
    s_comb4[wid][g][q * 2 + 1] = c1;
    if (q == 0) { s_bg[wid][g] = bg; s_node[wid][g] = valid ? train_inputs[bg] : -1; }
    const int tyv = valid ? train_types[bg] : 0;
    const unsigned long long vm = __ballot(valid);
    __syncthreads();
    if (vm == 0ull) return;                       // whole wave is padding
    const int t0 = __shfl(tyv, (int)(__ffsll((long long)vm) - 1), 64);

    const int  c   = lane;
    const bool act = c < EMB / 4;                 // 50 float4 chunks

    // batch-issue all 16 node-row gathers so HBM latency hides under the tw loop
    float4 nv[16];
    #pragma unroll
    for (int gg = 0; gg < 16; ++gg) {
        const int nd = s_node[wid][gg];
        float4 t = make_float4(0.f, 0.f, 0.f, 0.f);
        if (act && nd >= 0) t = *(const float4*)(node_emb + (size_t)nd * EMB + c * 4);
        nv[gg] = t;
    }

    const float* twp = tw + (size_t)t0 * U_DIM * EMB + c * 4;
    const float* scp = (const float*)&s_comb4[wid][0][0];   // [16][32]
    float4 acc[16];
    #pragma unroll
    for (int gg = 0; gg < 16; ++gg) acc[gg] = make_float4(0.f, 0.f, 0.f, 0.f);

    #pragma unroll 4
    for (int uu = 0; uu < U_DIM; ++uu) {
        float4 wv = make_float4(0.f, 0.f, 0.f, 0.f);
        if (act) wv = *(const float4*)(twp + uu * EMB);
        #pragma unroll
        for (int gg = 0; gg < 16; ++gg) {
            const float cg = scp[gg * 32 + uu];
            acc[gg].x += cg * wv.x; acc[gg].y += cg * wv.y;
            acc[gg].z += cg * wv.z; acc[gg].w += cg * wv.w;
        }
    }

    #pragma unroll
    for (int gg = 0; gg < 16; ++gg) {
        const int bg2 = s_bg[wid][gg];
        float4 v = make_float4(acc[gg].x + nv[gg].x, acc[gg].y + nv[gg].y,
                               acc[gg].z + nv[gg].z, acc[gg].w + nv[gg].w);
        float ss = v.x * v.x + v.y * v.y + v.z * v.z + v.w * v.w;
        #pragma unroll
        for (int m = 1; m < 64; m <<= 1) ss += __shfl_xor(ss, m, 64);
        const float rinv = 1.f / fmaxf(sqrtf(ss), 1e-12f);
        if (act && bg2 >= 0) {
            float4 o = make_float4(v.x * rinv, v.y * rinv, v.z * rinv, v.w * rinv);
            *(float4*)(out + (size_t)bg2 * EMB + c * 4) = o;
        }
    }
}

// ---------------- launch ----------------

extern "C" void kernel_launch(void* const* d_in, const int* in_sizes, int n_in,
                              void* d_out, int out_size, void* d_ws, size_t ws_size,
                              hipStream_t stream) {
    const int*   train_inputs = (const int*)d_in[0];
    const int*   train_types  = (const int*)d_in[1];
    const int*   node_neigh   = (const int*)d_in[2];
    const float* node_emb     = (const float*)d_in[3];
    const float* node_type_e  = (const float*)d_in[4];
    const float* tw           = (const float*)d_in[5];
    const float* tw1          = (const float*)d_in[6];
    const float* tw2          = (const float*)d_in[7];
    float*       out          = (float*)d_out;

    const int B  = in_sizes[0];          // 16384
    const int pb = B + 64;               // padded perm size (multiple of 64)

    int*   perm  = (int*)d_ws;
    int*   cnt   = perm + pb;
    int*   fill  = cnt + 4;
    float* combw = (float*)d_ws + pb + 8;   // 16B-aligned: (pb+8) % 4 == 0

    k_init   <<<(pb + 255) / 256, 256, 0, stream>>>(perm, cnt, pb);
    k_count  <<<B / 1024, 1024, 0, stream>>>(train_types, cnt);
    k_base   <<<1, 64, 0, stream>>>(cnt, fill);
    k_scatter<<<B / 1024, 1024, 0, stream>>>(train_types, fill, perm);

    k_comb   <<<B / WAVES, WAVES * 64, 0, stream>>>(
        train_types, node_neigh, node_type_e, tw1, tw2, combw);

    k_embed  <<<pb / (16 * WAVES), WAVES * 64, 0, stream>>>(
        train_inputs, train_types, perm, combw, node_emb, tw, out);
}

// Round 3
// 36.371 us; speedup vs baseline: 1.4706x; 1.4706x over previous
//
#include <hip/hip_runtime.h>

#define EMB 200
#define U_DIM 32
#define T_DIM 4
#define DIM_A 32
#define NN 10
#define BLK 512
#define NWAVE 8
#define BPW 8
#define TW_FLOATS (T_DIM * U_DIM * EMB)   // 25600 floats = 102400 B

__global__ __launch_bounds__(BLK, 2) void gatne_fused(
    const int* __restrict__ train_inputs,
    const int* __restrict__ train_types,
    const int* __restrict__ node_neigh,
    const float* __restrict__ node_emb,
    const float* __restrict__ node_type_emb,
    const float* __restrict__ tw,
    const float* __restrict__ tw1,
    const float* __restrict__ tw2,
    float* __restrict__ out)
{
    __shared__ float s_tw[TW_FLOATS];                 // 102.4 KB: all 4 type slices
    __shared__ float s_nte[NWAVE][T_DIM][U_DIM];      // 4 KB
    __shared__ float s_comb[NWAVE][U_DIM];            // 1 KB

    const int wid  = threadIdx.x >> 6;
    const int lane = threadIdx.x & 63;
    const int u    = lane & 31;
    const int th   = lane >> 5;
    const int base = blockIdx.x * (NWAVE * BPW);

    // prologue: issue b0's neighbor-index load before staging
    int nb[2];
    nb[0] = (lane < T_DIM * NN) ? node_neigh[(base + wid) * T_DIM * NN + lane] : 0;
    nb[1] = 0;

    // ---- stage all of tw into LDS (one-time, ~102 KB from L2) ----
    {
        const float4* src = (const float4*)tw;
        float4*       dst = (float4*)s_tw;
        #pragma unroll
        for (int k = 0; k < 13; ++k) {
            const int i = threadIdx.x + k * BLK;
            if (i < TW_FLOATS / 4) dst[i] = src[i];
        }
    }
    __syncthreads();

    // gather staging registers: g[buf][tt][n], double-buffered
    float g[2][2][NN];

    // issue gathers for b0
    #pragma unroll
    for (int tt = 0; tt < 2; ++tt) {
        const int t = tt * 2 + th;
        #pragma unroll
        for (int n = 0; n < NN; ++n) {
            const int idx = __shfl(nb[0], t * NN + n, 64);
            g[0][tt][n] = node_type_emb[((long)idx * T_DIM + t) * U_DIM + u];
        }
    }

    #pragma unroll
    for (int i = 0; i < BPW; ++i) {
        const int cb   = i & 1;
        const int nbuf = cb ^ 1;
        const int b    = base + i * NWAVE + wid;

        // issue next b's neighbor indices (address for next gathers)
        if (i + 1 < BPW)
            nb[nbuf] = (lane < T_DIM * NN)
                     ? node_neigh[(base + (i + 1) * NWAVE + wid) * T_DIM * NN + lane] : 0;

        const int type = train_types[b];     // wave-uniform
        const int node = train_inputs[b];    // wave-uniform

        // issue this b's node-embedding row load early
        float4 nv = make_float4(0.f, 0.f, 0.f, 0.f);
        if (lane < EMB / 4)
            nv = *(const float4*)(node_emb + (size_t)node * EMB + lane * 4);

        // reduce staged gathers -> s_nte
        #pragma unroll
        for (int tt = 0; tt < 2; ++tt) {
            const int t = tt * 2 + th;
            float a0 = 0.f;
            #pragma unroll
            for (int n = 0; n < NN; ++n) a0 += g[cb][tt][n];
            s_nte[wid][t][u] = a0;
        }

        // attention
        const float* tw1p = tw1 + type * U_DIM * DIM_A;
        const float  w2   = tw2[type * DIM_A + u];
        float sc[2];
        #pragma unroll
        for (int tt = 0; tt < 2; ++tt) {
            const int t = tt * 2 + th;
            float a1 = 0.f;
            #pragma unroll
            for (int uu = 0; uu < U_DIM; ++uu)
                a1 += s_nte[wid][t][uu] * tw1p[uu * DIM_A + u];
            float s = tanhf(a1) * w2;
            #pragma unroll
            for (int m = 1; m < 32; m <<= 1) s += __shfl_xor(s, m, 64);
            sc[tt] = s;
        }
        const float o0 = __shfl_xor(sc[0], 32, 64);
        const float o1 = __shfl_xor(sc[1], 32, 64);
        const float s0 = th ? o0    : sc[0];
        const float s1 = th ? sc[0] : o0;
        const float s2 = th ? o1    : sc[1];
        const float s3 = th ? sc[1] : o1;

        const float mx  = fmaxf(fmaxf(s0, s1), fmaxf(s2, s3));
        const float e0  = __expf(s0 - mx), e1 = __expf(s1 - mx);
        const float e2  = __expf(s2 - mx), e3 = __expf(s3 - mx);
        const float inv = 1.f / (e0 + e1 + e2 + e3);
        const float comb = (e0 * s_nte[wid][0][u] + e1 * s_nte[wid][1][u] +
                            e2 * s_nte[wid][2][u] + e3 * s_nte[wid][3][u]) * inv;
        if (lane < 32) s_comb[wid][u] = comb;

        // issue gathers for NEXT b now — they fly under the matvec below (T14)
        if (i + 1 < BPW) {
            #pragma unroll
            for (int tt = 0; tt < 2; ++tt) {
                const int t = tt * 2 + th;
                #pragma unroll
                for (int n = 0; n < NN; ++n) {
                    const int idx = __shfl(nb[nbuf], t * NN + n, 64);
                    g[nbuf][tt][n] = node_type_emb[((long)idx * T_DIM + t) * U_DIM + u];
                }
            }
        }

        // matvec from LDS-resident tw
        const float* twp = s_tw + type * U_DIM * EMB;
        float4 v = nv;
        if (lane < EMB / 4) {
            #pragma unroll
            for (int uu = 0; uu < U_DIM; ++uu) {
                const float  cg = s_comb[wid][uu];
                const float4 w  = *(const float4*)(twp + uu * EMB + lane * 4);
                v.x += cg * w.x; v.y += cg * w.y; v.z += cg * w.z; v.w += cg * w.w;
            }
        }
        float ss = (lane < EMB / 4) ? (v.x * v.x + v.y * v.y + v.z * v.z + v.w * v.w) : 0.f;
        #pragma unroll
        for (int m = 1; m < 64; m <<= 1) ss += __shfl_xor(ss, m, 64);
        const float rinv = 1.f / fmaxf(sqrtf(ss), 1e-12f);
        if (lane < EMB / 4) {
            float4 o = make_float4(v.x * rinv, v.y * rinv, v.z * rinv, v.w * rinv);
            *(float4*)(out + (size_t)b * EMB + lane * 4) = o;
        }
    }
}

extern "C" void kernel_launch(void* const* d_in, const int* in_sizes, int n_in,
                              void* d_out, int out_size, void* d_ws, size_t ws_size,
                              hipStream_t stream) {
    const int*   train_inputs = (const int*)d_in[0];
    const int*   train_types  = (const int*)d_in[1];
    const int*   node_neigh   = (const int*)d_in[2];
    const float* node_emb     = (const float*)d_in[3];
    const float* node_type_e  = (const float*)d_in[4];
    const float* tw           = (const float*)d_in[5];
    const float* tw1          = (const float*)d_in[6];
    const float* tw2          = (const float*)d_in[7];
    float*       out          = (float*)d_out;

    const int B = in_sizes[0];                 // 16384
    const int blocks = B / (NWAVE * BPW);      // 256 — one block per CU

    gatne_fused<<<blocks, BLK, 0, stream>>>(
        train_inputs, train_types, node_neigh,
        node_emb, node_type_e, tw, tw1, tw2, out);
}